// Round 3
// baseline (679.439 us; speedup 1.0000x reference)
//
#include <hip/hip_runtime.h>

#define KDIM 128

// ---------------------------------------------------------------------------
// CSR build: histogram of src, exclusive scan, scatter (dst -> col), row sort
// ---------------------------------------------------------------------------
__global__ void hist_kernel(const int* __restrict__ src, int* __restrict__ cnt, int E) {
    int i = blockIdx.x * blockDim.x + threadIdx.x;
    if (i < E) atomicAdd(&cnt[src[i]], 1);
}

__global__ void scan_kernel(const int* __restrict__ cnt, int* __restrict__ row_ptr,
                            int* __restrict__ cursor, int N) {
    __shared__ int wsum[16];
    __shared__ int base_sh;
    const int tid = threadIdx.x;
    const int lane = tid & 63;
    const int w = tid >> 6;
    if (tid == 0) base_sh = 0;
    __syncthreads();
    for (int base = 0; base < N; base += 1024) {
        int i = base + tid;
        int v = (i < N) ? cnt[i] : 0;
        int x = v;
        #pragma unroll
        for (int off = 1; off < 64; off <<= 1) {
            int t = __shfl_up(x, off);
            if (lane >= off) x += t;
        }
        if (lane == 63) wsum[w] = x;
        __syncthreads();
        if (tid < 16) {
            int t = wsum[tid];
            #pragma unroll
            for (int off = 1; off < 16; off <<= 1) {
                int u = __shfl_up(t, off);
                if (tid >= off) t += u;
            }
            wsum[tid] = t;  // inclusive over waves
        }
        __syncthreads();
        int wexcl = (w == 0) ? 0 : wsum[w - 1];
        int excl = base_sh + wexcl + (x - v);
        if (i < N) { row_ptr[i] = excl; cursor[i] = excl; }
        int total = wsum[15];
        __syncthreads();
        if (tid == 0) base_sh += total;
        __syncthreads();
    }
    if (threadIdx.x == 0) row_ptr[N] = base_sh;
}

__global__ void scatter_kernel(const int* __restrict__ src, const int* __restrict__ dst,
                               int* cursor, int* __restrict__ col, int E) {
    int i = blockIdx.x * blockDim.x + threadIdx.x;
    if (i < E) {
        int p = atomicAdd(&cursor[src[i]], 1);
        col[p] = dst[i];
    }
}

// Sort each CSR row's col values ascending -> deterministic summation order.
__global__ void sortrows_kernel(const int* __restrict__ row_ptr, int* __restrict__ col, int M) {
    int wid = (blockIdx.x * blockDim.x + threadIdx.x) >> 6;
    int lane = threadIdx.x & 63;
    if (wid >= M) return;
    int s = row_ptr[wid], e = row_ptr[wid + 1], len = e - s;
    if (len <= 1) return;
    if (len <= 64) {
        int v = (lane < len) ? col[s + lane] : 0x7fffffff;
        #pragma unroll
        for (int k = 2; k <= 64; k <<= 1) {
            #pragma unroll
            for (int j = k >> 1; j > 0; j >>= 1) {
                int o = __shfl_xor(v, j);
                bool dir = ((lane & k) == 0);      // ascending block?
                bool smaller = ((lane & j) == 0);  // lower partner?
                int mn = min(v, o), mx = max(v, o);
                v = (dir == smaller) ? mn : mx;
            }
        }
        if (lane < len) col[s + lane] = v;
    } else if (lane == 0) {
        // rare fallback (deg > 64): insertion sort in global memory
        for (int a = s + 1; a < e; a++) {
            int key = col[a];
            int b = a - 1;
            while (b >= s && col[b] > key) { col[b + 1] = col[b]; b--; }
            col[b + 1] = key;
        }
    }
}

// ---------------------------------------------------------------------------
// MaxK: keep top-32 of 128 per row (jax.lax.top_k tie-break: lower index wins)
// One wave per row; ballot+popcount radix select. Emits dense hs (for GEMM)
// plus compressed (vals f32[32], idx u8[32]) in ascending-index order.
// ---------------------------------------------------------------------------
__global__ void maxk_kernel(const float* __restrict__ h, float* __restrict__ hs,
                            float* __restrict__ cvals, unsigned char* __restrict__ cidx,
                            int M) {
    int wid = (blockIdx.x * blockDim.x + threadIdx.x) >> 6;
    int lane = threadIdx.x & 63;
    if (wid >= M) return;
    float2 v = ((const float2*)(h + (size_t)wid * KDIM))[lane];

    // orderable keys: larger float <-> larger uint
    unsigned int u0 = __float_as_uint(v.x);
    u0 = (u0 & 0x80000000u) ? ~u0 : (u0 | 0x80000000u);
    unsigned int u1 = __float_as_uint(v.y);
    u1 = (u1 & 0x80000000u) ? ~u1 : (u1 | 0x80000000u);

    // MSB radix select: find T = key of the 32nd largest element
    unsigned int prefix = 0;
    int remaining = 32;
    #pragma unroll
    for (int b = 31; b >= 0; --b) {
        unsigned int candHi = (prefix >> b) | 1u;  // high bits (31..b) of candidate
        unsigned long long m0 = __ballot((u0 >> b) == candHi);
        unsigned long long m1 = __ballot((u1 >> b) == candHi);
        int cnt = __popcll(m0) + __popcll(m1);
        if (cnt >= remaining) prefix |= (1u << b);
        else remaining -= cnt;
    }

    // keep all keys > T; among == T keep lowest element indices (idx = 2*lane+j)
    unsigned long long e0 = __ballot(u0 == prefix);
    unsigned long long e1 = __ballot(u1 == prefix);
    unsigned long long g0 = __ballot(u0 > prefix);
    unsigned long long g1 = __ballot(u1 > prefix);
    int quota = 32 - (__popcll(g0) + __popcll(g1));  // how many ==T to keep
    unsigned long long below = (1ULL << lane) - 1ULL;
    int rank0 = __popcll(e0 & below) + __popcll(e1 & below);
    int rank1 = rank0 + (int)((e0 >> lane) & 1ULL);
    bool k0 = (u0 > prefix) || (((e0 >> lane) & 1ULL) && rank0 < quota);
    bool k1 = (u1 > prefix) || (((e1 >> lane) & 1ULL) && rank1 < quota);

    float2 o;
    o.x = k0 ? v.x : 0.0f;
    o.y = k1 ? v.y : 0.0f;
    ((float2*)(hs + (size_t)wid * KDIM))[lane] = o;

    // compressed output: compaction rank in ascending element-index order
    unsigned long long km0 = __ballot(k0);
    unsigned long long km1 = __ballot(k1);
    int c0 = __popcll(km0 & below) + __popcll(km1 & below);
    int c1 = c0 + (k0 ? 1 : 0);
    size_t base = (size_t)wid * 32;
    if (k0) { cvals[base + c0] = v.x; cidx[base + c0] = (unsigned char)(2 * lane); }
    if (k1) { cvals[base + c1] = v.y; cidx[base + c1] = (unsigned char)(2 * lane + 1); }
}

// ---------------------------------------------------------------------------
// Aggregation from compressed hs: agg[s] = (sum over row s of sparse rows)/deg
// One wave per node; 2 edges/iter (half-wave each); per-half LDS accumulators
// (no same-address collisions within an edge -> deterministic, no atomcount).
// Gather footprint: 8 MB (vs 25.6 MB dense) -> much better L2 residency.
// ---------------------------------------------------------------------------
__global__ __launch_bounds__(256)
void aggregate_kernel(const float* __restrict__ cvals, const unsigned char* __restrict__ cidx,
                      const int* __restrict__ row_ptr, const int* __restrict__ col,
                      float* __restrict__ agg, int M) {
    __shared__ float acc[4][2][KDIM];   // [wave][half][feat]
    const int w = threadIdx.x >> 6;
    const int lane = threadIdx.x & 63;
    const int wid = (blockIdx.x * blockDim.x + threadIdx.x) >> 6;
    const int half = lane >> 5;
    const int l32 = lane & 31;

    // zero this wave's accumulators (2 per half-pair, 4 floats/lane total)
    acc[w][0][lane] = 0.0f;
    acc[w][0][lane + 64] = 0.0f;
    acc[w][1][lane] = 0.0f;
    acc[w][1][lane + 64] = 0.0f;
    __syncthreads();   // grid is exact (M % 4 == 0), all waves participate

    if (wid < M) {
        int s = row_ptr[wid], e = row_ptr[wid + 1];
        float* a = acc[w][half];
        for (int j = s + half; j < e; j += 2) {
            int c = col[j];
            float val = cvals[(size_t)c * 32 + l32];
            int id = cidx[(size_t)c * 32 + l32];
            atomicAdd(&a[id], val);   // distinct ids within an edge -> ordered per wave
        }
    }
    __syncthreads();
    if (wid < M) {
        int s = row_ptr[wid], e = row_ptr[wid + 1];
        float inv = 1.0f / ((float)(e - s) + 1e-6f);
        float2 o;
        o.x = (acc[w][0][2 * lane]     + acc[w][1][2 * lane])     * inv;
        o.y = (acc[w][0][2 * lane + 1] + acc[w][1][2 * lane + 1]) * inv;
        ((float2*)(agg + (size_t)wid * KDIM))[lane] = o;
    }
}

// ---------------------------------------------------------------------------
// f32 GEMM: C[M,BN] = A1[M,128] @ B1[128,BN] (+ A2 @ B2) (+ bias)
// 256 threads, 8x8 register tile each; block tile (16384/BN) x BN.
// ---------------------------------------------------------------------------
template <int BN, bool DUAL, bool BIAS>
__global__ __launch_bounds__(256, 3)
void gemm_f32(const float* __restrict__ A1, const float* __restrict__ B1,
              const float* __restrict__ A2, const float* __restrict__ B2,
              const float* __restrict__ bias, float* __restrict__ C, int M) {
    constexpr int BM = 16384 / BN;   // 128 (BN=128) or 256 (BN=64)
    constexpr int KC = 32;
    constexpr int BMP = BM + 4;
    constexpr int BNP = BN + 4;
    constexpr int TCX = BN / 8;      // 16 or 8

    __shared__ float As[KC][BMP];    // transposed: As[k][m]
    __shared__ float Bs[KC][BNP];

    const int tid = threadIdx.x;
    const int tx = tid % TCX;
    const int ty = tid / TCX;
    const int row0 = blockIdx.x * BM;

    float acc[8][8];
    #pragma unroll
    for (int r = 0; r < 8; r++)
        #pragma unroll
        for (int c = 0; c < 8; c++) acc[r][c] = 0.0f;

    const int nsrc = DUAL ? 2 : 1;
    for (int src = 0; src < nsrc; src++) {
        const float* A = (src == 0) ? A1 : A2;
        const float* B = (src == 0) ? B1 : B2;
        for (int kc = 0; kc < KDIM; kc += KC) {
            // stage A chunk (BM x KC), float4 along K, store transposed
            #pragma unroll
            for (int q = 0; q < (BM * KC / 4) / 256; q++) {
                int idx = tid + q * 256;
                int m = idx >> 3;       // KC/4 = 8 float4 per row
                int kq = idx & 7;
                float4 v = make_float4(0.f, 0.f, 0.f, 0.f);
                int row = row0 + m;
                if (row < M) v = *(const float4*)(A + (size_t)row * KDIM + kc + kq * 4);
                As[kq * 4 + 0][m] = v.x;
                As[kq * 4 + 1][m] = v.y;
                As[kq * 4 + 2][m] = v.z;
                As[kq * 4 + 3][m] = v.w;
            }
            // stage B chunk (KC x BN)
            #pragma unroll
            for (int q = 0; q < (KC * BN / 4) / 256; q++) {
                int idx = tid + q * 256;
                int n4 = idx % (BN / 4);
                int kr = idx / (BN / 4);
                float4 v = *(const float4*)(B + (size_t)(kc + kr) * BN + n4 * 4);
                *(float4*)&Bs[kr][n4 * 4] = v;
            }
            __syncthreads();
            #pragma unroll 8
            for (int kk = 0; kk < KC; kk++) {
                float4 a0 = *(const float4*)&As[kk][ty * 8];
                float4 a1 = *(const float4*)&As[kk][ty * 8 + 4];
                float4 b0 = *(const float4*)&Bs[kk][tx * 4];
                float4 b1 = *(const float4*)&Bs[kk][BN / 2 + tx * 4];
                float av[8] = {a0.x, a0.y, a0.z, a0.w, a1.x, a1.y, a1.z, a1.w};
                float bv[8] = {b0.x, b0.y, b0.z, b0.w, b1.x, b1.y, b1.z, b1.w};
                #pragma unroll
                for (int r = 0; r < 8; r++)
                    #pragma unroll
                    for (int c = 0; c < 8; c++)
                        acc[r][c] += av[r] * bv[c];
            }
            __syncthreads();
        }
    }

    // epilogue
    #pragma unroll
    for (int r = 0; r < 8; r++) {
        int row = row0 + ty * 8 + r;
        if (row >= M) continue;
        float4 o0, o1;
        o0.x = acc[r][0]; o0.y = acc[r][1]; o0.z = acc[r][2]; o0.w = acc[r][3];
        o1.x = acc[r][4]; o1.y = acc[r][5]; o1.z = acc[r][6]; o1.w = acc[r][7];
        if (BIAS) {
            o0.x += bias[tx * 4 + 0]; o0.y += bias[tx * 4 + 1];
            o0.z += bias[tx * 4 + 2]; o0.w += bias[tx * 4 + 3];
            o1.x += bias[BN / 2 + tx * 4 + 0]; o1.y += bias[BN / 2 + tx * 4 + 1];
            o1.z += bias[BN / 2 + tx * 4 + 2]; o1.w += bias[BN / 2 + tx * 4 + 3];
        }
        *(float4*)(C + (size_t)row * BN + tx * 4) = o0;
        *(float4*)(C + (size_t)row * BN + BN / 2 + tx * 4) = o1;
    }
}

// ---------------------------------------------------------------------------
extern "C" void kernel_launch(void* const* d_in, const int* in_sizes, int n_in,
                              void* d_out, int out_size, void* d_ws, size_t ws_size,
                              hipStream_t stream) {
    const float* x       = (const float*)d_in[0];
    const float* W_in    = (const float*)d_in[1];
    const float* b_in    = (const float*)d_in[2];
    const float* W_self  = (const float*)d_in[3];
    const float* W_neigh = (const float*)d_in[4];
    const float* W_out   = (const float*)d_in[5];
    const float* b_out   = (const float*)d_in[6];
    const int*   eidx    = (const int*)d_in[7];

    const int N = 50000, E = 800000;
    const int* src = eidx;
    const int* dst = eidx + E;

    char* ws = (char*)d_ws;
    float* h   = (float*)(ws);                  // 25.6 MB
    float* hs  = (float*)(ws + 25600000);       // 25.6 MB
    float* agg = (float*)(ws + 51200000);       // 25.6 MB
    int* cnt     = (int*)(ws + 76800000);       // 200 KB
    int* row_ptr = (int*)(ws + 77000000);       // 200 KB
    int* cursor  = (int*)(ws + 77200016);       // 200 KB
    int* col     = (int*)(ws + 77400016);       // 3.2 MB
    float* cvals = (float*)(ws + 80600016);     // 6.4 MB
    unsigned char* cidx = (unsigned char*)(ws + 87000016);  // 1.6 MB (ends ~88.6 MB)

    hipMemsetAsync(cnt, 0, N * sizeof(int), stream);
    hist_kernel<<<(E + 255) / 256, 256, 0, stream>>>(src, cnt, E);
    scan_kernel<<<1, 1024, 0, stream>>>(cnt, row_ptr, cursor, N);
    scatter_kernel<<<(E + 255) / 256, 256, 0, stream>>>(src, dst, cursor, col, E);
    sortrows_kernel<<<(N + 3) / 4, 256, 0, stream>>>(row_ptr, col, N);

    // h = x @ W_in + b_in
    gemm_f32<128, false, true><<<(N + 127) / 128, 256, 0, stream>>>(
        x, W_in, nullptr, nullptr, b_in, h, N);

    for (int i = 0; i < 2; i++) {
        maxk_kernel<<<(N + 3) / 4, 256, 0, stream>>>(h, hs, cvals, cidx, N);
        aggregate_kernel<<<(N + 3) / 4, 256, 0, stream>>>(cvals, cidx, row_ptr, col, agg, N);
        // h = hs @ W_self[i] + agg @ W_neigh[i]
        gemm_f32<128, true, false><<<(N + 127) / 128, 256, 0, stream>>>(
            hs, W_self + (size_t)i * KDIM * KDIM,
            agg, W_neigh + (size_t)i * KDIM * KDIM,
            nullptr, h, N);
    }

    // out = h @ W_out + b_out
    gemm_f32<64, false, true><<<(N + 255) / 256, 256, 0, stream>>>(
        h, W_out, nullptr, nullptr, b_out, (float*)d_out, N);
}

// Round 4
// 517.306 us; speedup vs baseline: 1.3134x; 1.3134x over previous
//
#include <hip/hip_runtime.h>

#define KDIM 128

// ---------------------------------------------------------------------------
// CSR build: histogram of src, exclusive scan, scatter (dst -> col), row sort
// ---------------------------------------------------------------------------
__global__ void hist_kernel(const int* __restrict__ src, int* __restrict__ cnt, int E) {
    int i = blockIdx.x * blockDim.x + threadIdx.x;
    if (i < E) atomicAdd(&cnt[src[i]], 1);
}

__global__ void scan_kernel(const int* __restrict__ cnt, int* __restrict__ row_ptr,
                            int* __restrict__ cursor, int N) {
    __shared__ int wsum[16];
    __shared__ int base_sh;
    const int tid = threadIdx.x;
    const int lane = tid & 63;
    const int w = tid >> 6;
    if (tid == 0) base_sh = 0;
    __syncthreads();
    for (int base = 0; base < N; base += 1024) {
        int i = base + tid;
        int v = (i < N) ? cnt[i] : 0;
        int x = v;
        #pragma unroll
        for (int off = 1; off < 64; off <<= 1) {
            int t = __shfl_up(x, off);
            if (lane >= off) x += t;
        }
        if (lane == 63) wsum[w] = x;
        __syncthreads();
        if (tid < 16) {
            int t = wsum[tid];
            #pragma unroll
            for (int off = 1; off < 16; off <<= 1) {
                int u = __shfl_up(t, off);
                if (tid >= off) t += u;
            }
            wsum[tid] = t;  // inclusive over waves
        }
        __syncthreads();
        int wexcl = (w == 0) ? 0 : wsum[w - 1];
        int excl = base_sh + wexcl + (x - v);
        if (i < N) { row_ptr[i] = excl; cursor[i] = excl; }
        int total = wsum[15];
        __syncthreads();
        if (tid == 0) base_sh += total;
        __syncthreads();
    }
    if (threadIdx.x == 0) row_ptr[N] = base_sh;
}

__global__ void scatter_kernel(const int* __restrict__ src, const int* __restrict__ dst,
                               int* cursor, int* __restrict__ col, int E) {
    int i = blockIdx.x * blockDim.x + threadIdx.x;
    if (i < E) {
        int p = atomicAdd(&cursor[src[i]], 1);
        col[p] = dst[i];
    }
}

// Sort each CSR row's col values ascending -> deterministic summation order.
__global__ void sortrows_kernel(const int* __restrict__ row_ptr, int* __restrict__ col, int M) {
    int wid = (blockIdx.x * blockDim.x + threadIdx.x) >> 6;
    int lane = threadIdx.x & 63;
    if (wid >= M) return;
    int s = row_ptr[wid], e = row_ptr[wid + 1], len = e - s;
    if (len <= 1) return;
    if (len <= 64) {
        int v = (lane < len) ? col[s + lane] : 0x7fffffff;
        #pragma unroll
        for (int k = 2; k <= 64; k <<= 1) {
            #pragma unroll
            for (int j = k >> 1; j > 0; j >>= 1) {
                int o = __shfl_xor(v, j);
                bool dir = ((lane & k) == 0);      // ascending block?
                bool smaller = ((lane & j) == 0);  // lower partner?
                int mn = min(v, o), mx = max(v, o);
                v = (dir == smaller) ? mn : mx;
            }
        }
        if (lane < len) col[s + lane] = v;
    } else if (lane == 0) {
        // rare fallback (deg > 64): insertion sort in global memory
        for (int a = s + 1; a < e; a++) {
            int key = col[a];
            int b = a - 1;
            while (b >= s && col[b] > key) { col[b + 1] = col[b]; b--; }
            col[b + 1] = key;
        }
    }
}

// ---------------------------------------------------------------------------
// MaxK: keep top-32 of 128 per row (jax.lax.top_k tie-break: lower index wins)
// One wave per row; ballot+popcount radix select (no cross-lane data moves).
// ---------------------------------------------------------------------------
__global__ void maxk_kernel(const float* __restrict__ h, float* __restrict__ hs, int M) {
    int wid = (blockIdx.x * blockDim.x + threadIdx.x) >> 6;
    int lane = threadIdx.x & 63;
    if (wid >= M) return;
    float2 v = ((const float2*)(h + (size_t)wid * KDIM))[lane];

    // orderable keys: larger float <-> larger uint
    unsigned int u0 = __float_as_uint(v.x);
    u0 = (u0 & 0x80000000u) ? ~u0 : (u0 | 0x80000000u);
    unsigned int u1 = __float_as_uint(v.y);
    u1 = (u1 & 0x80000000u) ? ~u1 : (u1 | 0x80000000u);

    // MSB radix select: find T = key of the 32nd largest element
    unsigned int prefix = 0;
    int remaining = 32;
    #pragma unroll
    for (int b = 31; b >= 0; --b) {
        unsigned int candHi = (prefix >> b) | 1u;  // high bits (31..b) of candidate
        unsigned long long m0 = __ballot((u0 >> b) == candHi);
        unsigned long long m1 = __ballot((u1 >> b) == candHi);
        int cnt = __popcll(m0) + __popcll(m1);
        if (cnt >= remaining) prefix |= (1u << b);
        else remaining -= cnt;
    }

    // keep all keys > T; among == T keep lowest element indices (idx = 2*lane+j)
    unsigned long long e0 = __ballot(u0 == prefix);
    unsigned long long e1 = __ballot(u1 == prefix);
    unsigned long long g0 = __ballot(u0 > prefix);
    unsigned long long g1 = __ballot(u1 > prefix);
    int quota = 32 - (__popcll(g0) + __popcll(g1));  // how many ==T to keep
    unsigned long long below = (1ULL << lane) - 1ULL;
    int rank0 = __popcll(e0 & below) + __popcll(e1 & below);
    int rank1 = rank0 + (int)((e0 >> lane) & 1ULL);
    bool k0 = (u0 > prefix) || (((e0 >> lane) & 1ULL) && rank0 < quota);
    bool k1 = (u1 > prefix) || (((e1 >> lane) & 1ULL) && rank1 < quota);

    float2 o;
    o.x = k0 ? v.x : 0.0f;
    o.y = k1 ? v.y : 0.0f;
    ((float2*)(hs + (size_t)wid * KDIM))[lane] = o;
}

// ---------------------------------------------------------------------------
// Aggregation: agg[s] = (sum over CSR row s of hs[col]) / (deg + 1e-6)
// One wave per node. 2 half-waves x 4-chain unroll = up to 8 independent
// 512B float4 row loads in flight per wave (latency hiding via MLP).
// Deterministic fixed combine order: chains 0..3, then half0 + half1.
// ---------------------------------------------------------------------------
__global__ __launch_bounds__(256)
void aggregate_kernel(const float* __restrict__ hs, const int* __restrict__ row_ptr,
                      const int* __restrict__ col, float* __restrict__ agg, int M) {
    const int lane = threadIdx.x & 63;
    const int wid = (blockIdx.x * blockDim.x + threadIdx.x) >> 6;
    if (wid >= M) return;
    const int half = lane >> 5;
    const int l32 = lane & 31;
    const int s = row_ptr[wid], e = row_ptr[wid + 1];
    const float4* __restrict__ hp = (const float4*)hs;  // row c -> hp[c*32 + l32]

    float4 a0 = make_float4(0.f, 0.f, 0.f, 0.f);
    float4 a1 = a0, a2 = a0, a3 = a0;

    int j = s + half;  // this half handles edges (j - s) even/odd per half
    for (; j + 6 < e; j += 8) {
        int c0 = col[j];
        int c1 = col[j + 2];
        int c2 = col[j + 4];
        int c3 = col[j + 6];
        float4 v0 = hp[(size_t)c0 * 32 + l32];
        float4 v1 = hp[(size_t)c1 * 32 + l32];
        float4 v2 = hp[(size_t)c2 * 32 + l32];
        float4 v3 = hp[(size_t)c3 * 32 + l32];
        a0.x += v0.x; a0.y += v0.y; a0.z += v0.z; a0.w += v0.w;
        a1.x += v1.x; a1.y += v1.y; a1.z += v1.z; a1.w += v1.w;
        a2.x += v2.x; a2.y += v2.y; a2.z += v2.z; a2.w += v2.w;
        a3.x += v3.x; a3.y += v3.y; a3.z += v3.z; a3.w += v3.w;
    }
    for (; j < e; j += 2) {  // tail for this half (deterministic: into a0)
        int c = col[j];
        float4 v = hp[(size_t)c * 32 + l32];
        a0.x += v.x; a0.y += v.y; a0.z += v.z; a0.w += v.w;
    }

    // combine chains in fixed order: ((a0 + a1) + a2) + a3
    float4 t;
    t.x = ((a0.x + a1.x) + a2.x) + a3.x;
    t.y = ((a0.y + a1.y) + a2.y) + a3.y;
    t.z = ((a0.z + a1.z) + a2.z) + a3.z;
    t.w = ((a0.w + a1.w) + a2.w) + a3.w;

    // cross-half combine: lane<32 gets half0 + half1 (fixed order)
    float4 u;
    u.x = __shfl_xor(t.x, 32);
    u.y = __shfl_xor(t.y, 32);
    u.z = __shfl_xor(t.z, 32);
    u.w = __shfl_xor(t.w, 32);

    if (half == 0) {
        float inv = 1.0f / ((float)(e - s) + 1e-6f);
        float4 o;
        o.x = (t.x + u.x) * inv;
        o.y = (t.y + u.y) * inv;
        o.z = (t.z + u.z) * inv;
        o.w = (t.w + u.w) * inv;
        ((float4*)(agg + (size_t)wid * KDIM))[l32] = o;
    }
}

// ---------------------------------------------------------------------------
// f32 GEMM: C[M,BN] = A1[M,128] @ B1[128,BN] (+ A2 @ B2) (+ bias)
// 256 threads, 8x8 register tile each; block tile (16384/BN) x BN.
// ---------------------------------------------------------------------------
template <int BN, bool DUAL, bool BIAS>
__global__ __launch_bounds__(256, 3)
void gemm_f32(const float* __restrict__ A1, const float* __restrict__ B1,
              const float* __restrict__ A2, const float* __restrict__ B2,
              const float* __restrict__ bias, float* __restrict__ C, int M) {
    constexpr int BM = 16384 / BN;   // 128 (BN=128) or 256 (BN=64)
    constexpr int KC = 32;
    constexpr int BMP = BM + 4;
    constexpr int BNP = BN + 4;
    constexpr int TCX = BN / 8;      // 16 or 8

    __shared__ float As[KC][BMP];    // transposed: As[k][m]
    __shared__ float Bs[KC][BNP];

    const int tid = threadIdx.x;
    const int tx = tid % TCX;
    const int ty = tid / TCX;
    const int row0 = blockIdx.x * BM;

    float acc[8][8];
    #pragma unroll
    for (int r = 0; r < 8; r++)
        #pragma unroll
        for (int c = 0; c < 8; c++) acc[r][c] = 0.0f;

    const int nsrc = DUAL ? 2 : 1;
    for (int src = 0; src < nsrc; src++) {
        const float* A = (src == 0) ? A1 : A2;
        const float* B = (src == 0) ? B1 : B2;
        for (int kc = 0; kc < KDIM; kc += KC) {
            // stage A chunk (BM x KC), float4 along K, store transposed
            #pragma unroll
            for (int q = 0; q < (BM * KC / 4) / 256; q++) {
                int idx = tid + q * 256;
                int m = idx >> 3;       // KC/4 = 8 float4 per row
                int kq = idx & 7;
                float4 v = make_float4(0.f, 0.f, 0.f, 0.f);
                int row = row0 + m;
                if (row < M) v = *(const float4*)(A + (size_t)row * KDIM + kc + kq * 4);
                As[kq * 4 + 0][m] = v.x;
                As[kq * 4 + 1][m] = v.y;
                As[kq * 4 + 2][m] = v.z;
                As[kq * 4 + 3][m] = v.w;
            }
            // stage B chunk (KC x BN)
            #pragma unroll
            for (int q = 0; q < (KC * BN / 4) / 256; q++) {
                int idx = tid + q * 256;
                int n4 = idx % (BN / 4);
                int kr = idx / (BN / 4);
                float4 v = *(const float4*)(B + (size_t)(kc + kr) * BN + n4 * 4);
                *(float4*)&Bs[kr][n4 * 4] = v;
            }
            __syncthreads();
            #pragma unroll 8
            for (int kk = 0; kk < KC; kk++) {
                float4 a0 = *(const float4*)&As[kk][ty * 8];
                float4 a1 = *(const float4*)&As[kk][ty * 8 + 4];
                float4 b0 = *(const float4*)&Bs[kk][tx * 4];
                float4 b1 = *(const float4*)&Bs[kk][BN / 2 + tx * 4];
                float av[8] = {a0.x, a0.y, a0.z, a0.w, a1.x, a1.y, a1.z, a1.w};
                float bv[8] = {b0.x, b0.y, b0.z, b0.w, b1.x, b1.y, b1.z, b1.w};
                #pragma unroll
                for (int r = 0; r < 8; r++)
                    #pragma unroll
                    for (int c = 0; c < 8; c++)
                        acc[r][c] += av[r] * bv[c];
            }
            __syncthreads();
        }
    }

    // epilogue
    #pragma unroll
    for (int r = 0; r < 8; r++) {
        int row = row0 + ty * 8 + r;
        if (row >= M) continue;
        float4 o0, o1;
        o0.x = acc[r][0]; o0.y = acc[r][1]; o0.z = acc[r][2]; o0.w = acc[r][3];
        o1.x = acc[r][4]; o1.y = acc[r][5]; o1.z = acc[r][6]; o1.w = acc[r][7];
        if (BIAS) {
            o0.x += bias[tx * 4 + 0]; o0.y += bias[tx * 4 + 1];
            o0.z += bias[tx * 4 + 2]; o0.w += bias[tx * 4 + 3];
            o1.x += bias[BN / 2 + tx * 4 + 0]; o1.y += bias[BN / 2 + tx * 4 + 1];
            o1.z += bias[BN / 2 + tx * 4 + 2]; o1.w += bias[BN / 2 + tx * 4 + 3];
        }
        *(float4*)(C + (size_t)row * BN + tx * 4) = o0;
        *(float4*)(C + (size_t)row * BN + BN / 2 + tx * 4) = o1;
    }
}

// ---------------------------------------------------------------------------
extern "C" void kernel_launch(void* const* d_in, const int* in_sizes, int n_in,
                              void* d_out, int out_size, void* d_ws, size_t ws_size,
                              hipStream_t stream) {
    const float* x       = (const float*)d_in[0];
    const float* W_in    = (const float*)d_in[1];
    const float* b_in    = (const float*)d_in[2];
    const float* W_self  = (const float*)d_in[3];
    const float* W_neigh = (const float*)d_in[4];
    const float* W_out   = (const float*)d_in[5];
    const float* b_out   = (const float*)d_in[6];
    const int*   eidx    = (const int*)d_in[7];

    const int N = 50000, E = 800000;
    const int* src = eidx;
    const int* dst = eidx + E;

    char* ws = (char*)d_ws;
    float* h   = (float*)(ws);                  // 25.6 MB
    float* hs  = (float*)(ws + 25600000);       // 25.6 MB
    float* agg = (float*)(ws + 51200000);       // 25.6 MB
    int* cnt     = (int*)(ws + 76800000);       // 200 KB
    int* row_ptr = (int*)(ws + 77000000);       // 200 KB
    int* cursor  = (int*)(ws + 77200016);       // 200 KB
    int* col     = (int*)(ws + 77400016);       // 3.2 MB

    hipMemsetAsync(cnt, 0, N * sizeof(int), stream);
    hist_kernel<<<(E + 255) / 256, 256, 0, stream>>>(src, cnt, E);
    scan_kernel<<<1, 1024, 0, stream>>>(cnt, row_ptr, cursor, N);
    scatter_kernel<<<(E + 255) / 256, 256, 0, stream>>>(src, dst, cursor, col, E);
    sortrows_kernel<<<(N + 3) / 4, 256, 0, stream>>>(row_ptr, col, N);

    // h = x @ W_in + b_in
    gemm_f32<128, false, true><<<(N + 127) / 128, 256, 0, stream>>>(
        x, W_in, nullptr, nullptr, b_in, h, N);

    for (int i = 0; i < 2; i++) {
        maxk_kernel<<<(N + 3) / 4, 256, 0, stream>>>(h, hs, N);
        aggregate_kernel<<<(N + 3) / 4, 256, 0, stream>>>(hs, row_ptr, col, agg, N);
        // h = hs @ W_self[i] + agg @ W_neigh[i]
        gemm_f32<128, true, false><<<(N + 127) / 128, 256, 0, stream>>>(
            hs, W_self + (size_t)i * KDIM * KDIM,
            agg, W_neigh + (size_t)i * KDIM * KDIM,
            nullptr, h, N);
    }

    // out = h @ W_out + b_out
    gemm_f32<64, false, true><<<(N + 255) / 256, 256, 0, stream>>>(
        h, W_out, nullptr, nullptr, b_out, (float*)d_out, N);
}